// Round 10
// baseline (101.206 us; speedup 1.0000x reference)
//
#include <hip/hip_runtime.h>

#define NN 512
#define DD 64
#define FN 32

typedef unsigned short ushortT;
typedef __attribute__((ext_vector_type(4))) unsigned short us4;
typedef __attribute__((ext_vector_type(8))) short s8;     // 8 bf16 MFMA operand
typedef __attribute__((ext_vector_type(4))) float f4;     // MFMA accumulator

__device__ inline ushortT f2bf(float x) {
    unsigned u = __float_as_uint(x);
    return (ushortT)((u + 0x7FFFu + ((u >> 16) & 1u)) >> 16);   // RNE
}

// ---------------- Kernel 1: fill-style streaming (t + adj->bf16) + prep ----------------
// blocks 0..2047:    adj/ef stream: 4 rows/block, 1 row/wave (pure float4 traffic)
// blocks 2048..2175: prev -> prevT bf16 (one 64-row chunk each)
// blocks 2176..2239: nf -> bf16
// block  2240:       W1T, W2T, v3 (wave-parallel)
__global__ __launch_bounds__(256) void stream_prep_kernel(
    const float* __restrict__ prev, const float* __restrict__ adj,
    const float* __restrict__ nf,   const float* __restrict__ ef,
    const float* __restrict__ W1,   const float* __restrict__ W2,
    const float* __restrict__ W3,   const float* __restrict__ W4,
    ushortT* __restrict__ adjb,  ushortT* __restrict__ prevT,
    ushortT* __restrict__ nfb,   ushortT* __restrict__ W1T,
    ushortT* __restrict__ W2T,   float* __restrict__ v3,
    float* __restrict__ tbuf)
{
    const int bk = blockIdx.x, tid = threadIdx.x;

    if (bk < 2048) {                      // ---- adj/ef stream: row per wave
        const int lane = tid & 63, w = tid >> 6;
        const int row = bk * 4 + w;
        const float4* a4 = (const float4*)(adj + row * NN);
        const float4* e4 = (const float4*)(ef  + row * NN);
        float4 a0 = a4[lane], a1 = a4[64 + lane];
        float4 e0 = e4[lane], e1 = e4[64 + lane];
        float tp = a0.x*e0.x + a0.y*e0.y + a0.z*e0.z + a0.w*e0.w
                 + a1.x*e1.x + a1.y*e1.y + a1.z*e1.z + a1.w*e1.w;
        #pragma unroll
        for (int s = 1; s < 64; s <<= 1) tp += __shfl_xor(tp, s, 64);
        us4 o0 = { f2bf(a0.x), f2bf(a0.y), f2bf(a0.z), f2bf(a0.w) };
        us4 o1 = { f2bf(a1.x), f2bf(a1.y), f2bf(a1.z), f2bf(a1.w) };
        ((us4*)(adjb + row * NN))[lane]      = o0;
        ((us4*)(adjb + row * NN))[64 + lane] = o1;
        if (lane == 0) tbuf[row] = tp;
    } else if (bk < 2176) {               // ---- prev transpose (one 64-row chunk)
        __shared__ float T[64][65];
        const int bb = bk - 2048;
        const int b = bb >> 3, c = bb & 7;
        #pragma unroll
        for (int s = 0; s < 16; ++s) {
            int idx = s * 256 + tid;
            int jl = idx >> 6, d = idx & 63;
            T[jl][d] = prev[b * NN * DD + (c * 64 + jl) * DD + d];
        }
        __syncthreads();
        #pragma unroll
        for (int s = 0; s < 16; ++s) {
            int idx = s * 256 + tid;
            int d = idx >> 6, jl = idx & 63;
            prevT[b * DD * NN + d * NN + c * 64 + jl] = f2bf(T[jl][d]);
        }
    } else if (bk < 2240) {               // ---- nf convert (coalesced float4)
        const int base = (bk - 2176) * 4096;
        #pragma unroll
        for (int s = 0; s < 4; ++s) {
            int i = base + s * 1024 + tid * 4;
            float4 v = *(const float4*)(nf + i);
            us4 o = { f2bf(v.x), f2bf(v.y), f2bf(v.z), f2bf(v.w) };
            *(us4*)(nfb + i) = o;
        }
    } else {                              // ---- weights (v3 wave-parallel)
        __shared__ float vpart[4][64];
        for (int i = tid; i < DD * FN; i += 256) {
            int e = i >> 5, f = i & 31;
            W1T[i] = f2bf(W1[f * DD + e]);
        }
        for (int i = tid; i < DD * DD; i += 256) {
            int e = i >> 6, d = i & 63;
            W2T[i] = f2bf(W2[d * DD + e]);
        }
        {
            const int e = tid & 63, dg = tid >> 6;
            float s = 0.f;
            #pragma unroll
            for (int d0 = 0; d0 < 16; ++d0) {
                int d = dg * 16 + d0;
                s = fmaf(fmaxf(W4[d], 0.f), W3[d * DD + e], s);
            }
            vpart[dg][e] = s;
            __syncthreads();
            if (tid < 64)
                v3[tid] = vpart[0][tid] + vpart[1][tid]
                        + vpart[2][tid] + vpart[3][tid];
        }
    }
}

// ---------------- Kernel 2: lean MFMA gemm (no staging, all operands cache-warm) ----------------
// 512 blocks x 256 thr (4 waves); wave w owns K-slice [128w,128w+128); C-reduce in LDS.
#define CPITCH 68             // f32 per Cpart row (272 B)
__global__ __launch_bounds__(256) void gemm_kernel(
    const ushortT* __restrict__ adjb, const ushortT* __restrict__ prevT,
    const ushortT* __restrict__ nfb,  const ushortT* __restrict__ W1T,
    const ushortT* __restrict__ W2T,  const float* __restrict__ v3,
    const float* __restrict__ tbuf,   float* __restrict__ out)
{
    __shared__ __align__(16) float   Cpart[4 * 16 * CPITCH]; // 17408 B
    __shared__ __align__(16) ushortT PT[16 * 72];            //  2304 B

    const int tid  = threadIdx.x;
    const int lane = tid & 63;
    const int w    = __builtin_amdgcn_readfirstlane(tid >> 6);
    const int i0   = blockIdx.x * 16;
    const int b    = blockIdx.x >> 5;
    const int l15  = lane & 15, g = lane >> 4;

    // ---- ap partial = adj_slice @ prev_slice (4 k-steps x 4 n-tiles), A direct from adjb
    f4 zero = {0.f, 0.f, 0.f, 0.f};
    f4 acc[4] = {zero, zero, zero, zero};
    const ushortT* arow = adjb  + (i0 + l15) * NN + 128 * w + 8 * g;
    const ushortT* pb   = prevT + b * DD * NN + l15 * NN + 128 * w + 8 * g;
    #pragma unroll
    for (int ksl = 0; ksl < 4; ++ksl) {
        s8 A = *(const s8*)(arow + 32 * ksl);
        #pragma unroll
        for (int nt = 0; nt < 4; ++nt) {
            s8 B = *(const s8*)(pb + nt * 16 * NN + 32 * ksl);
            acc[nt] = __builtin_amdgcn_mfma_f32_16x16x32_bf16(A, B, acc[nt], 0, 0, 0);
        }
    }

    // ---- write C partials
    #pragma unroll
    for (int nt = 0; nt < 4; ++nt)
        #pragma unroll
        for (int r = 0; r < 4; ++r)
            Cpart[w * 16 * CPITCH + (4 * g + r) * CPITCH + 16 * nt + l15] = acc[nt][r];
    __syncthreads();

    // ---- reduce C across 4 waves -> PT (bf16, A-layout for ap@W2)
    {
        const int row = tid >> 4, c0 = (tid & 15) * 4;
        us4 o;
        #pragma unroll
        for (int c = 0; c < 4; ++c) {
            float s = Cpart[0 * 16 * CPITCH + row * CPITCH + c0 + c]
                    + Cpart[1 * 16 * CPITCH + row * CPITCH + c0 + c]
                    + Cpart[2 * 16 * CPITCH + row * CPITCH + c0 + c]
                    + Cpart[3 * 16 * CPITCH + row * CPITCH + c0 + c];
            o[c] = f2bf(s);
        }
        *(us4*)(&PT[row * 72 + c0]) = o;
    }
    __syncthreads();

    // ---- epilogue: wave w owns col-tile nt = w; t read direct from global
    float vv = v3[16 * w + l15];
    f4 o;
    #pragma unroll
    for (int r = 0; r < 4; ++r) o[r] = tbuf[i0 + 4 * g + r] * vv;

    s8 A1 = *(const s8*)(nfb + (i0 + l15) * FN + 8 * g);
    s8 B1 = *(const s8*)(W1T + (16 * w + l15) * FN + 8 * g);
    o = __builtin_amdgcn_mfma_f32_16x16x32_bf16(A1, B1, o, 0, 0, 0);

    #pragma unroll
    for (int k2 = 0; k2 < 2; ++k2) {
        s8 A2 = *(const s8*)(&PT[l15 * 72 + 32 * k2 + 8 * g]);
        s8 B2 = *(const s8*)(W2T + (16 * w + l15) * DD + 32 * k2 + 8 * g);
        o = __builtin_amdgcn_mfma_f32_16x16x32_bf16(A2, B2, o, 0, 0, 0);
    }

    float* orow = out + i0 * DD;
    #pragma unroll
    for (int r = 0; r < 4; ++r)
        orow[(4 * g + r) * DD + 16 * w + l15] = fmaxf(o[r], 0.f);
}

extern "C" void kernel_launch(void* const* d_in, const int* in_sizes, int n_in,
                              void* d_out, int out_size, void* d_ws, size_t ws_size,
                              hipStream_t stream) {
    const float* prev = (const float*)d_in[0];
    const float* adj  = (const float*)d_in[1];
    const float* nf   = (const float*)d_in[2];
    const float* ef   = (const float*)d_in[3];
    const float* W1   = (const float*)d_in[4];
    const float* W2   = (const float*)d_in[5];
    const float* W3   = (const float*)d_in[6];
    const float* W4   = (const float*)d_in[7];
    float* out = (float*)d_out;

    char* ws = (char*)d_ws;                                // byte offsets, 16B-aligned
    ushortT* adjb  = (ushortT*)(ws + 0);                   // 8,388,608 B
    ushortT* prevT = (ushortT*)(ws + 8388608);             // 1,048,576 B
    ushortT* nfb   = (ushortT*)(ws + 9437184);             //   524,288 B
    ushortT* W1T   = (ushortT*)(ws + 9961472);             //     4,096 B
    ushortT* W2T   = (ushortT*)(ws + 9965568);             //     8,192 B
    float*   v3    = (float*)  (ws + 9973760);             //       256 B
    float*   tbuf  = (float*)  (ws + 9974016);             //    32,768 B

    stream_prep_kernel<<<dim3(2241), dim3(256), 0, stream>>>(
        prev, adj, nf, ef, W1, W2, W3, W4, adjb, prevT, nfb, W1T, W2T, v3, tbuf);
    gemm_kernel<<<dim3(512), dim3(256), 0, stream>>>(
        adjb, prevT, nfb, W1T, W2T, v3, tbuf, out);
}

// Round 11
// 98.917 us; speedup vs baseline: 1.0231x; 1.0231x over previous
//
#include <hip/hip_runtime.h>

#define NN 512
#define DD 64
#define FN 32

typedef unsigned short ushortT;
typedef __attribute__((ext_vector_type(4))) unsigned short us4;
typedef __attribute__((ext_vector_type(8))) short s8;     // 8 bf16 MFMA operand
typedef __attribute__((ext_vector_type(4))) float f4;     // MFMA accumulator

__device__ inline ushortT f2bf(float x) {
    unsigned u = __float_as_uint(x);
    return (ushortT)((u + 0x7FFFu + ((u >> 16) & 1u)) >> 16);   // RNE
}

// ---------------- Kernel P: prevT + nf bf16 + weights (all parallel) ----------------
__global__ __launch_bounds__(256) void prep_kernel(
    const float* __restrict__ prev, const float* __restrict__ nf,
    const float* __restrict__ W1,   const float* __restrict__ W2,
    const float* __restrict__ W3,   const float* __restrict__ W4,
    ushortT* __restrict__ prevT, ushortT* __restrict__ nfb,
    ushortT* __restrict__ W1T,   ushortT* __restrict__ W2T,
    float* __restrict__ v3)
{
    const int bk = blockIdx.x, tid = threadIdx.x;

    if (bk < 128) {                       // ---- prev transpose (one 64-row chunk)
        __shared__ float T[64][65];
        const int b = bk >> 3, c = bk & 7;
        #pragma unroll
        for (int s = 0; s < 16; ++s) {
            int idx = s * 256 + tid;
            int jl = idx >> 6, d = idx & 63;
            T[jl][d] = prev[b * NN * DD + (c * 64 + jl) * DD + d];
        }
        __syncthreads();
        #pragma unroll
        for (int s = 0; s < 16; ++s) {
            int idx = s * 256 + tid;
            int d = idx >> 6, jl = idx & 63;
            prevT[b * DD * NN + d * NN + c * 64 + jl] = f2bf(T[jl][d]);
        }
    } else if (bk < 192) {                // ---- nf convert (coalesced float4)
        const int base = (bk - 128) * 4096;
        #pragma unroll
        for (int s = 0; s < 4; ++s) {
            int i = base + s * 1024 + tid * 4;
            float4 v = *(const float4*)(nf + i);
            us4 o = { f2bf(v.x), f2bf(v.y), f2bf(v.z), f2bf(v.w) };
            *(us4*)(nfb + i) = o;
        }
    } else {                              // ---- weights (v3 wave-parallel)
        __shared__ float vpart[4][64];
        for (int i = tid; i < DD * FN; i += 256) {
            int e = i >> 5, f = i & 31;
            W1T[i] = f2bf(W1[f * DD + e]);
        }
        for (int i = tid; i < DD * DD; i += 256) {
            int e = i >> 6, d = i & 63;
            W2T[i] = f2bf(W2[d * DD + e]);
        }
        {
            const int e = tid & 63, dg = tid >> 6;
            float s = 0.f;
            #pragma unroll
            for (int d0 = 0; d0 < 16; ++d0) {
                int d = dg * 16 + d0;
                s = fmaf(fmaxf(W4[d], 0.f), W3[d * DD + e], s);
            }
            vpart[dg][e] = s;
            __syncthreads();
            if (tid < 64)
                v3[tid] = vpart[0][tid] + vpart[1][tid]
                        + vpart[2][tid] + vpart[3][tid];
        }
    }
}

// ---------------- Kernel G: fused adj/ef load + t + MFMA, K split 4 ways ----------------
// block = 256 thr = 4 waves, 16 output rows. wave w owns K-slice [128w,128w+128).
#define APITCH 136            // bf16 elems per adjS row (272 B: 2-way bank alias)
#define CPITCH 68             // f32 per Cpart row (272 B)
__global__ __launch_bounds__(256) void gemm_kernel(
    const float* __restrict__ adj,   const float* __restrict__ ef,
    const ushortT* __restrict__ prevT, const ushortT* __restrict__ nfb,
    const ushortT* __restrict__ W1T, const ushortT* __restrict__ W2T,
    const float* __restrict__ v3,    float* __restrict__ out)
{
    __shared__ __align__(16) ushortT adjS[4 * 16 * APITCH];  // 17408 B
    __shared__ __align__(16) float   Cpart[4 * 16 * CPITCH]; // 17408 B
    __shared__ __align__(16) ushortT PT[16 * 72];            //  2304 B
    __shared__ float tpart[4][16];
    __shared__ float tsum[16];

    const int tid  = threadIdx.x;
    const int lane = tid & 63;
    const int w    = __builtin_amdgcn_readfirstlane(tid >> 6);
    const int i0   = blockIdx.x * 16;
    const int b    = blockIdx.x >> 5;
    const int l15  = lane & 15, g = lane >> 4;
    const int l31  = lane & 31, half = lane >> 5;

    // ---- phase A: load adj/ef fp32 (own K-slice), t-partial, convert -> LDS
    #pragma unroll
    for (int it = 0; it < 8; ++it) {
        const int r = 2 * it + half;
        const float4* a4 = (const float4*)(adj + (i0 + r) * NN + 128 * w);
        const float4* e4 = (const float4*)(ef  + (i0 + r) * NN + 128 * w);
        float4 av = a4[l31], ev = e4[l31];
        float tp = av.x*ev.x + av.y*ev.y + av.z*ev.z + av.w*ev.w;
        #pragma unroll
        for (int s = 1; s < 32; s <<= 1) tp += __shfl_xor(tp, s, 64);
        if (l31 == 0) tpart[w][r] = tp;
        us4 ov = { f2bf(av.x), f2bf(av.y), f2bf(av.z), f2bf(av.w) };
        *(us4*)(&adjS[w * 16 * APITCH + r * APITCH + 4 * l31]) = ov;
    }

    // ---- phase B: ap partial = adj_slice @ prev_slice (4 k-steps)
    f4 zero = {0.f, 0.f, 0.f, 0.f};
    f4 acc[4] = {zero, zero, zero, zero};
    const ushortT* pb = prevT + b * DD * NN + l15 * NN + 128 * w + 8 * g;
    #pragma unroll
    for (int ksl = 0; ksl < 4; ++ksl) {
        s8 A = *(const s8*)(&adjS[w * 16 * APITCH + l15 * APITCH + 32 * ksl + 8 * g]);
        #pragma unroll
        for (int nt = 0; nt < 4; ++nt) {
            s8 B = *(const s8*)(pb + nt * 16 * NN + 32 * ksl);
            acc[nt] = __builtin_amdgcn_mfma_f32_16x16x32_bf16(A, B, acc[nt], 0, 0, 0);
        }
    }

    // ---- write C partials
    #pragma unroll
    for (int nt = 0; nt < 4; ++nt)
        #pragma unroll
        for (int r = 0; r < 4; ++r)
            Cpart[w * 16 * CPITCH + (4 * g + r) * CPITCH + 16 * nt + l15] = acc[nt][r];
    __syncthreads();

    // ---- reduce C across waves -> PT (bf16, A-layout for ap@W2); reduce t
    {
        const int row = tid >> 4, c0 = (tid & 15) * 4;
        us4 o;
        #pragma unroll
        for (int c = 0; c < 4; ++c) {
            float s = Cpart[0 * 16 * CPITCH + row * CPITCH + c0 + c]
                    + Cpart[1 * 16 * CPITCH + row * CPITCH + c0 + c]
                    + Cpart[2 * 16 * CPITCH + row * CPITCH + c0 + c]
                    + Cpart[3 * 16 * CPITCH + row * CPITCH + c0 + c];
            o[c] = f2bf(s);
        }
        *(us4*)(&PT[row * 72 + c0]) = o;
        if (tid < 16)
            tsum[tid] = tpart[0][tid] + tpart[1][tid] + tpart[2][tid] + tpart[3][tid];
    }
    __syncthreads();

    // ---- epilogue: wave w owns col-tile nt = w
    float vv = v3[16 * w + l15];
    f4 o;
    #pragma unroll
    for (int r = 0; r < 4; ++r) o[r] = tsum[4 * g + r] * vv;

    s8 A1 = *(const s8*)(nfb + (i0 + l15) * FN + 8 * g);
    s8 B1 = *(const s8*)(W1T + (16 * w + l15) * FN + 8 * g);
    o = __builtin_amdgcn_mfma_f32_16x16x32_bf16(A1, B1, o, 0, 0, 0);

    #pragma unroll
    for (int k2 = 0; k2 < 2; ++k2) {
        s8 A2 = *(const s8*)(&PT[l15 * 72 + 32 * k2 + 8 * g]);
        s8 B2 = *(const s8*)(W2T + (16 * w + l15) * DD + 32 * k2 + 8 * g);
        o = __builtin_amdgcn_mfma_f32_16x16x32_bf16(A2, B2, o, 0, 0, 0);
    }

    float* orow = out + i0 * DD;
    #pragma unroll
    for (int r = 0; r < 4; ++r)
        orow[(4 * g + r) * DD + 16 * w + l15] = fmaxf(o[r], 0.f);
}

extern "C" void kernel_launch(void* const* d_in, const int* in_sizes, int n_in,
                              void* d_out, int out_size, void* d_ws, size_t ws_size,
                              hipStream_t stream) {
    const float* prev = (const float*)d_in[0];
    const float* adj  = (const float*)d_in[1];
    const float* nf   = (const float*)d_in[2];
    const float* ef   = (const float*)d_in[3];
    const float* W1   = (const float*)d_in[4];
    const float* W2   = (const float*)d_in[5];
    const float* W3   = (const float*)d_in[6];
    const float* W4   = (const float*)d_in[7];
    float* out = (float*)d_out;

    char* ws = (char*)d_ws;                                // byte offsets, 16B-aligned
    ushortT* prevT = (ushortT*)(ws + 0);                   // 1,048,576 B
    ushortT* nfb   = (ushortT*)(ws + 1048576);             //   524,288 B
    ushortT* W1T   = (ushortT*)(ws + 1572864);             //     4,096 B
    ushortT* W2T   = (ushortT*)(ws + 1576960);             //     8,192 B
    float*   v3    = (float*)  (ws + 1585152);             //       256 B

    prep_kernel<<<dim3(193), dim3(256), 0, stream>>>(
        prev, nf, W1, W2, W3, W4, prevT, nfb, W1T, W2T, v3);
    gemm_kernel<<<dim3(512), dim3(256), 0, stream>>>(
        adj, ef, prevT, nfb, W1T, W2T, v3, out);
}

// Round 12
// 95.863 us; speedup vs baseline: 1.0557x; 1.0319x over previous
//
#include <hip/hip_runtime.h>

#define NN 512
#define DD 64
#define FN 32

typedef unsigned short ushortT;
typedef __attribute__((ext_vector_type(4))) unsigned short us4;
typedef __attribute__((ext_vector_type(8))) short s8;     // 8 bf16 MFMA operand
typedef __attribute__((ext_vector_type(4))) float f4;     // MFMA accumulator

__device__ inline ushortT f2bf(float x) {
    unsigned u = __float_as_uint(x);
    return (ushortT)((u + 0x7FFFu + ((u >> 16) & 1u)) >> 16);   // RNE
}

// ---------------- Single fused kernel ----------------
// 256 blocks (1/CU) x 512 thr (8 waves). Block owns 32 output rows of batch b.
// LDS: adjS 32x520 bf16 | prevS 64x520 bf16 (transposed) | PT 32x72 | W2S | W1S | v3
// Wave wv = (rh, nt): output tile rows [16rh,16rh+16), cols [16nt,16nt+16), full K=512.
#define AP 520               // bf16 pitch (1040 B) for adjS/prevS rows
__global__ __launch_bounds__(512) void fused_kernel(
    const float* __restrict__ prev, const float* __restrict__ adj,
    const float* __restrict__ nf,   const float* __restrict__ ef,
    const float* __restrict__ W1,   const float* __restrict__ W2,
    const float* __restrict__ W3,   const float* __restrict__ W4,
    float* __restrict__ out)
{
    __shared__ __align__(16) ushortT adjS[32 * AP];   // 33280 B
    __shared__ __align__(16) ushortT prevS[64 * AP];  // 66560 B
    __shared__ __align__(16) ushortT PT[32 * 72];     //  4608 B
    __shared__ __align__(16) ushortT W2S[64 * 64];    //  8192 B
    __shared__ __align__(16) ushortT W1S[64 * 32];    //  4096 B
    __shared__ float vpart[8][64];                    //  2048 B
    __shared__ float v3S[64];
    __shared__ float tsum[32];

    const int tid  = threadIdx.x;
    const int lane = tid & 63;
    const int wv   = __builtin_amdgcn_readfirstlane(tid >> 6);  // 0..7
    const int blk  = blockIdx.x;
    const int i0   = blk * 32;
    const int b    = blk >> 4;           // 16 blocks per batch
    const int l15  = lane & 15, g = lane >> 4;
    const int rh   = wv >> 2, nt = wv & 3;

    // ---- phase A1: adj/ef -> t partial + adjS (row = tid>>4, 32-col chunk = tid&15)
    {
        const int r = tid >> 4, c16 = tid & 15;
        const float4* ag = (const float4*)(adj + (i0 + r) * NN + c16 * 32);
        const float4* eg = (const float4*)(ef  + (i0 + r) * NN + c16 * 32);
        float tp = 0.f;
        #pragma unroll
        for (int it = 0; it < 8; ++it) {
            float4 av = ag[it], ev = eg[it];
            tp += av.x*ev.x + av.y*ev.y + av.z*ev.z + av.w*ev.w;
            us4 ov = { f2bf(av.x), f2bf(av.y), f2bf(av.z), f2bf(av.w) };
            *(us4*)(&adjS[r * AP + c16 * 32 + it * 4]) = ov;
        }
        tp += __shfl_xor(tp, 1, 64);
        tp += __shfl_xor(tp, 2, 64);
        tp += __shfl_xor(tp, 4, 64);
        tp += __shfl_xor(tp, 8, 64);
        if ((lane & 15) == 0) tsum[r] = tp;
    }

    // ---- phase A2: prev[b] -> prevS transposed bf16
    {
        const float4* pb = (const float4*)(prev + b * NN * DD);
        #pragma unroll
        for (int s = 0; s < 16; ++s) {
            int fidx = s * 512 + tid;            // 0..8191
            int j = fidx >> 4, d4 = (fidx & 15) * 4;
            float4 v = pb[fidx];
            prevS[(d4 + 0) * AP + j] = f2bf(v.x);
            prevS[(d4 + 1) * AP + j] = f2bf(v.y);
            prevS[(d4 + 2) * AP + j] = f2bf(v.z);
            prevS[(d4 + 3) * AP + j] = f2bf(v.w);
        }
    }

    // ---- phase A3: weights -> W2S/W1S/vpart
    {
        #pragma unroll
        for (int k = 0; k < 2; ++k) {            // W2S[e*64+d] = W2[d][e]
            int fi = tid * 2 + k;                // 0..1023
            int d = fi >> 4, e4 = (fi & 15) * 4;
            float4 v = ((const float4*)W2)[fi];
            W2S[(e4 + 0) * 64 + d] = f2bf(v.x);
            W2S[(e4 + 1) * 64 + d] = f2bf(v.y);
            W2S[(e4 + 2) * 64 + d] = f2bf(v.z);
            W2S[(e4 + 3) * 64 + d] = f2bf(v.w);
        }
        {                                        // W1S[e*32+f] = W1[f][e]
            int fi = tid;                        // 0..511
            int f = fi >> 4, e4 = (fi & 15) * 4;
            float4 v = ((const float4*)W1)[fi];
            W1S[(e4 + 0) * 32 + f] = f2bf(v.x);
            W1S[(e4 + 1) * 32 + f] = f2bf(v.y);
            W1S[(e4 + 2) * 32 + f] = f2bf(v.z);
            W1S[(e4 + 3) * 32 + f] = f2bf(v.w);
        }
        const int e = tid & 63, dg = tid >> 6;   // vpart: 8 d's per group
        float s = 0.f;
        #pragma unroll
        for (int d0 = 0; d0 < 8; ++d0) {
            int d = dg * 8 + d0;
            s = fmaf(fmaxf(W4[d], 0.f), W3[d * DD + e], s);
        }
        vpart[dg][e] = s;
    }
    __syncthreads();                             // barrier 1

    // ---- phase B: ap tile = adjS(16 rows) @ prevS(16 cols), K=512, 16 k-steps
    f4 acc = {0.f, 0.f, 0.f, 0.f};
    #pragma unroll
    for (int ks = 0; ks < 16; ++ks) {
        s8 A  = *(const s8*)(&adjS[(16 * rh + l15) * AP + 32 * ks + 8 * g]);
        s8 Bf = *(const s8*)(&prevS[(16 * nt + l15) * AP + 32 * ks + 8 * g]);
        acc = __builtin_amdgcn_mfma_f32_16x16x32_bf16(A, Bf, acc, 0, 0, 0);
    }
    #pragma unroll
    for (int r = 0; r < 4; ++r)                  // C-layout -> PT (A-layout rows)
        PT[(16 * rh + 4 * g + r) * 72 + 16 * nt + l15] = f2bf(acc[r]);

    if (tid < 64) {                              // v3 finalize (vpart pre-barrier1)
        float s = 0.f;
        #pragma unroll
        for (int dg = 0; dg < 8; ++dg) s += vpart[dg][tid];
        v3S[tid] = s;
    }
    __syncthreads();                             // barrier 2

    // ---- epilogue: o = t*v3 + nf@W1 + ap@W2, relu, store
    float vv = v3S[16 * nt + l15];
    f4 o;
    #pragma unroll
    for (int r = 0; r < 4; ++r) o[r] = tsum[16 * rh + 4 * g + r] * vv;

    {   // A1 = nf rows (fp32 -> bf16 inline)
        const float* nrow = nf + (i0 + 16 * rh + l15) * FN + 8 * g;
        float4 n0 = *(const float4*)(nrow);
        float4 n1 = *(const float4*)(nrow + 4);
        s8 A1;
        A1[0] = (short)f2bf(n0.x); A1[1] = (short)f2bf(n0.y);
        A1[2] = (short)f2bf(n0.z); A1[3] = (short)f2bf(n0.w);
        A1[4] = (short)f2bf(n1.x); A1[5] = (short)f2bf(n1.y);
        A1[6] = (short)f2bf(n1.z); A1[7] = (short)f2bf(n1.w);
        s8 B1 = *(const s8*)(&W1S[(16 * nt + l15) * 32 + 8 * g]);
        o = __builtin_amdgcn_mfma_f32_16x16x32_bf16(A1, B1, o, 0, 0, 0);
    }
    #pragma unroll
    for (int k2 = 0; k2 < 2; ++k2) {
        s8 A2 = *(const s8*)(&PT[(16 * rh + l15) * 72 + 32 * k2 + 8 * g]);
        s8 B2 = *(const s8*)(&W2S[(16 * nt + l15) * 64 + 32 * k2 + 8 * g]);
        o = __builtin_amdgcn_mfma_f32_16x16x32_bf16(A2, B2, o, 0, 0, 0);
    }

    #pragma unroll
    for (int r = 0; r < 4; ++r)
        out[(i0 + 16 * rh + 4 * g + r) * DD + 16 * nt + l15] = fmaxf(o[r], 0.f);
}

extern "C" void kernel_launch(void* const* d_in, const int* in_sizes, int n_in,
                              void* d_out, int out_size, void* d_ws, size_t ws_size,
                              hipStream_t stream) {
    const float* prev = (const float*)d_in[0];
    const float* adj  = (const float*)d_in[1];
    const float* nf   = (const float*)d_in[2];
    const float* ef   = (const float*)d_in[3];
    const float* W1   = (const float*)d_in[4];
    const float* W2   = (const float*)d_in[5];
    const float* W3   = (const float*)d_in[6];
    const float* W4   = (const float*)d_in[7];
    float* out = (float*)d_out;

    fused_kernel<<<dim3(256), dim3(512), 0, stream>>>(
        prev, adj, nf, ef, W1, W2, W3, W4, out);
}